// Round 14
// baseline (29.252 us; speedup 1.0000x reference)
//
#include <hip/hip_runtime.h>
#include <hip/hip_bf16.h>

// SpeakerEmbedder: token histogram (bag-of-words mean) -> 3-layer MLP -> L2 normalize.
// B=64, T=16384, VOCAB=1024, HIDDEN=512, EMBED=256. All math in fp32.
//
// Round-13: all sync mechanisms cost ~3us/boundary (graph gap == MALL flag
// handoff; measured across r5/r10/r12 which all land 26-28.5us). So minimize
// TOTAL sync points and use only kernel boundaries (free correct visibility,
// no flags/memset/correctness risk):
//   k1: dense1 with FUSED PER-BLOCK HISTOGRAM (each (rg,jw) block re-histograms
//       its own 4 rows in LDS; 16x redundant but ~2.5us < boundary+roundtrip).
//       Pooled never touches global. 512 thr (8 waves/CU) for latency hiding.
//   k2: dense2 (proven r10 structure, plain in/out).
//   k3: dense3 FULL-ROW blocks (64 blocks x 512 thr, one row each, all 256
//       cols; K-split across waves) -> ssq block-local -> norm in-block.
// 3 nodes, 2 gaps, zero workspace protocol state.

#define VOCAB 1024
#define HIDDEN 512
#define EMBED 256
#define TOK_T 16384
#define BATCH 64

#define XSIDX(k) ((k) + ((k) >> 6))  // LDS pad: k-groups land on distinct banks

// ---------------------------------------------------------------------------
// Kernel 1: fused hist + dense1 (1024 -> 512, relu).
// Grid 256 = 16 rowgroups(4 rows) x 16 j-windows(32 cols); 512 threads.
// Hist: 128 thr/row, 4 per-row LDS histograms (no cross-row contention).
// Dense: 32 kg x 16 jt; thread tile 4 rows x 2 cols; KC=32.
// ---------------------------------------------------------------------------
__global__ __launch_bounds__(512) void k1_hist_dense1(const int* __restrict__ tokens,
                                                      const float* __restrict__ W1,
                                                      const float* __restrict__ b1,
                                                      float* __restrict__ h1) {
    __shared__ float4 xs4[VOCAB + VOCAB / 64];  // pooled transposed [k][4 rows], 16.25 KB
    __shared__ union {
        unsigned cnt[4 * VOCAB];                // hist phase: [row][vocab], 16 KB
        float part[32][4][32];                  // dense reduce phase, 16 KB
    } u;

    const int tid = threadIdx.x;
    const int rg = blockIdx.x >> 4;
    const int jw = blockIdx.x & 15;
    const int b0 = rg * 4;

    // ---- per-row histograms of this block's 4 rows ----
#pragma unroll
    for (int i = 0; i < 8; ++i) u.cnt[tid + 512 * i] = 0u;
    __syncthreads();
    {
        const int r = tid >> 7;    // 0..3 (wave-uniform groups of 2 waves)
        const int lt = tid & 127;  // 0..127 within row
        const int4* __restrict__ t4 =
            reinterpret_cast<const int4*>(tokens + (size_t)(b0 + r) * TOK_T);
        unsigned* __restrict__ c = u.cnt + r * VOCAB;
#pragma unroll
        for (int i = 0; i < TOK_T / 4 / 128; ++i) {  // 32 iterations
            int4 v = t4[lt + 128 * i];               // coalesced 1KB/wave
            atomicAdd(&c[v.x & (VOCAB - 1)], 1u);
            atomicAdd(&c[v.y & (VOCAB - 1)], 1u);
            atomicAdd(&c[v.z & (VOCAB - 1)], 1u);
            atomicAdd(&c[v.w & (VOCAB - 1)], 1u);
        }
    }
    __syncthreads();

    // ---- counts -> pooled (/T), transposed into xs4 ----
    {
        const float invT = 1.0f / (float)TOK_T;
#pragma unroll
        for (int ko = 0; ko < 2; ++ko) {
            const int k = tid + 512 * ko;
            float4 v;
            v.x = (float)u.cnt[k] * invT;
            v.y = (float)u.cnt[k + VOCAB] * invT;
            v.z = (float)u.cnt[k + 2 * VOCAB] * invT;
            v.w = (float)u.cnt[k + 3 * VOCAB] * invT;
            xs4[XSIDX(k)] = v;
        }
    }
    __syncthreads();  // cnt reads done before part writes (union)

    // ---- dense1 compute: 32 kg x 16 jt, thread tile 4 rows x 2 cols ----
    {
        constexpr int KG = 32, KC = VOCAB / KG, OUT = HIDDEN;  // KC=32
        const int jt = tid & 15;
        const int kg = tid >> 4;
        const float* __restrict__ w = W1 + (size_t)(kg * KC) * OUT + jw * 32 + jt * 2;

        float2 a0 = {0.f, 0.f}, a1 = {0.f, 0.f}, a2 = {0.f, 0.f}, a3 = {0.f, 0.f};
#pragma unroll 8
        for (int ks = 0; ks < KC; ++ks) {
            const int k = kg * KC + ks;
            const float4 xv = xs4[XSIDX(k)];                       // <=2-way alias (free)
            const float2 wv = *(const float2*)(w + (size_t)ks * OUT);  // coalesced
            a0.x = fmaf(xv.x, wv.x, a0.x); a0.y = fmaf(xv.x, wv.y, a0.y);
            a1.x = fmaf(xv.y, wv.x, a1.x); a1.y = fmaf(xv.y, wv.y, a1.y);
            a2.x = fmaf(xv.z, wv.x, a2.x); a2.y = fmaf(xv.z, wv.y, a2.y);
            a3.x = fmaf(xv.w, wv.x, a3.x); a3.y = fmaf(xv.w, wv.y, a3.y);
        }
        *(float2*)&u.part[kg][0][jt * 2] = a0;
        *(float2*)&u.part[kg][1][jt * 2] = a1;
        *(float2*)&u.part[kg][2][jt * 2] = a2;
        *(float2*)&u.part[kg][3][jt * 2] = a3;
        __syncthreads();

        if (tid < 128) {
            const int r = tid >> 5;   // 0..3
            const int jl = tid & 31;  // 0..31
            float s = b1[jw * 32 + jl];
#pragma unroll
            for (int g = 0; g < KG; ++g) s += u.part[g][r][jl];
            h1[(size_t)(b0 + r) * OUT + jw * 32 + jl] = fmaxf(s, 0.0f);  // plain store
        }
    }
}

// ---------------------------------------------------------------------------
// Kernel 2: dense2 (512 -> 512, relu). Proven r10 structure, plain in/out.
// Grid 256 = 16 rg x 16 jw; 256 thr = 16 kg x 16 jt; tile 4 rows x 2 cols.
// ---------------------------------------------------------------------------
__global__ __launch_bounds__(256) void k2_dense2(const float* __restrict__ h1,
                                                 const float* __restrict__ W2,
                                                 const float* __restrict__ b2,
                                                 float* __restrict__ h2) {
    __shared__ float4 xs4[HIDDEN + HIDDEN / 64];
    __shared__ float part[16][4][32];
    const int tid = threadIdx.x;
    const int rg = blockIdx.x >> 4;
    const int jw = blockIdx.x & 15;
    const int b0 = rg * 4;

    for (int k = tid; k < HIDDEN; k += 256) {
        float4 v;
        v.x = h1[(size_t)(b0 + 0) * HIDDEN + k];
        v.y = h1[(size_t)(b0 + 1) * HIDDEN + k];
        v.z = h1[(size_t)(b0 + 2) * HIDDEN + k];
        v.w = h1[(size_t)(b0 + 3) * HIDDEN + k];
        xs4[XSIDX(k)] = v;
    }
    __syncthreads();

    constexpr int KG = 16, KC = HIDDEN / KG, OUT = HIDDEN;  // KC=32
    const int jt = tid & 15;
    const int kg = tid >> 4;
    const float* __restrict__ w = W2 + (size_t)(kg * KC) * OUT + jw * 32 + jt * 2;

    float2 a0 = {0.f, 0.f}, a1 = {0.f, 0.f}, a2 = {0.f, 0.f}, a3 = {0.f, 0.f};
#pragma unroll 8
    for (int ks = 0; ks < KC; ++ks) {
        const int k = kg * KC + ks;
        const float4 xv = xs4[XSIDX(k)];
        const float2 wv = *(const float2*)(w + (size_t)ks * OUT);
        a0.x = fmaf(xv.x, wv.x, a0.x); a0.y = fmaf(xv.x, wv.y, a0.y);
        a1.x = fmaf(xv.y, wv.x, a1.x); a1.y = fmaf(xv.y, wv.y, a1.y);
        a2.x = fmaf(xv.z, wv.x, a2.x); a2.y = fmaf(xv.z, wv.y, a2.y);
        a3.x = fmaf(xv.w, wv.x, a3.x); a3.y = fmaf(xv.w, wv.y, a3.y);
    }
    *(float2*)&part[kg][0][jt * 2] = a0;
    *(float2*)&part[kg][1][jt * 2] = a1;
    *(float2*)&part[kg][2][jt * 2] = a2;
    *(float2*)&part[kg][3][jt * 2] = a3;
    __syncthreads();

    if (tid < 128) {
        const int r = tid >> 5;
        const int jl = tid & 31;
        float s = b2[jw * 32 + jl];
#pragma unroll
        for (int g = 0; g < KG; ++g) s += part[g][r][jl];
        h2[(size_t)(b0 + r) * OUT + jw * 32 + jl] = fmaxf(s, 0.0f);  // plain store
    }
}

// ---------------------------------------------------------------------------
// Kernel 3: dense3 (512 -> 256) + L2 normalize, one FULL row per block.
// Grid 64 x 512 thr = 8 kg x 64 jt (float4 cols); ssq block-local.
// ---------------------------------------------------------------------------
__global__ __launch_bounds__(512) void k3_dense3_norm(const float* __restrict__ h2,
                                                      const float* __restrict__ W3,
                                                      const float* __restrict__ b3,
                                                      float* __restrict__ out) {
    __shared__ float xrow[HIDDEN];
    __shared__ float red[8 * EMBED];  // [kg][col], 8 KB
    __shared__ float wss[4];
    const int tid = threadIdx.x;
    const int row = blockIdx.x;

    xrow[tid] = h2[(size_t)row * HIDDEN + tid];  // 512 thr, 512 elems
    __syncthreads();

    constexpr int KG = 8, KC = HIDDEN / KG;  // KC=64
    const int jt = tid & 63;   // 64 jt x float4 = 256 cols
    const int kg = tid >> 6;   // 8 k-groups (one per wave)
    const float* __restrict__ w = W3 + (size_t)(kg * KC) * EMBED + jt * 4;

    float4 a = {0.f, 0.f, 0.f, 0.f};
#pragma unroll 8
    for (int ks = 0; ks < KC; ++ks) {
        const float x = xrow[kg * KC + ks];                          // wave-uniform bcast
        const float4 wv = *(const float4*)(w + (size_t)ks * EMBED);  // 1KB/wave coalesced
        a.x = fmaf(x, wv.x, a.x); a.y = fmaf(x, wv.y, a.y);
        a.z = fmaf(x, wv.z, a.z); a.w = fmaf(x, wv.w, a.w);
    }
    *(float4*)&red[kg * EMBED + jt * 4] = a;
    __syncthreads();

    float s = 0.0f;
    if (tid < EMBED) {
        s = b3[tid];
#pragma unroll
        for (int g = 0; g < KG; ++g) s += red[g * EMBED + tid];
    }
    float ss = s * s;  // 0 for tid >= 256
#pragma unroll
    for (int off = 32; off > 0; off >>= 1) ss += __shfl_down(ss, off);  // wave64
    if (tid < EMBED && (tid & 63) == 0) wss[tid >> 6] = ss;
    __syncthreads();
    if (tid < EMBED) {
        const float total = wss[0] + wss[1] + wss[2] + wss[3];
        out[(size_t)row * EMBED + tid] = s / fmaxf(sqrtf(total), 1e-12f);  // F.normalize eps
    }
}

// ---------------------------------------------------------------------------
// Launch: 3 plain kernels. No flags, no atomics to global, no memset.
// ---------------------------------------------------------------------------
extern "C" void kernel_launch(void* const* d_in, const int* in_sizes, int n_in,
                              void* d_out, int out_size, void* d_ws, size_t ws_size,
                              hipStream_t stream) {
    const int*   tokens = (const int*)d_in[0];   // [64,16384], values in [0,1024)
    const float* W1     = (const float*)d_in[1]; // [1024,512]
    const float* b1     = (const float*)d_in[2]; // [512]
    const float* W2     = (const float*)d_in[3]; // [512,512]
    const float* b2     = (const float*)d_in[4]; // [512]
    const float* W3     = (const float*)d_in[5]; // [512,256]
    const float* b3     = (const float*)d_in[6]; // [256]
    float*       out    = (float*)d_out;         // [64,256]

    // Workspace: only h1/h2 (fully rewritten every call).
    uint8_t* base = (uint8_t*)d_ws;
    float* h1 = (float*)(base);             // [64][512] = 128 KB
    float* h2 = (float*)(base + 0x20000);   // [64][512] = 128 KB

    k1_hist_dense1<<<256, 512, 0, stream>>>(tokens, W1, b1, h1);
    k2_dense2<<<256, 256, 0, stream>>>(h1, W2, b2, h2);
    k3_dense3_norm<<<64, 512, 0, stream>>>(h2, W3, b3, out);
}